// Round 5
// baseline (119.251 us; speedup 1.0000x reference)
//
#include <hip/hip_runtime.h>
#include <cstdint>

#define E_DIM   1024
#define DH      32
#define M_FEAT  256
#define BT      16384

typedef __attribute__((ext_vector_type(8))) _Float16 f16x8;
typedef __attribute__((ext_vector_type(4))) float f32x4;

// ws layout (shorts=fp16): proj W in MFMA-fragment order, flat = (nt*32 + sub)*512 + lane*8
// single fp16 panel (no l-term for weights), 128 KB total

__device__ __forceinline__ unsigned packh2(_Float16 a, _Float16 b) {
    union { _Float16 h[2]; unsigned u; } t;
    t.h[0] = a; t.h[1] = b;
    return t.u;
}

// x/z 2-term fp16 split: h = fp16_rne(f), l = fp16_rne(f - h)
__device__ __forceinline__ void splitf16_2(float f0, float f1, unsigned& ph, unsigned& pl) {
    _Float16 h0 = (_Float16)f0, h1 = (_Float16)f1;
    float l0 = f0 - (float)h0, l1 = f1 - (float)h1;
    ph = packh2(h0, h1);
    pl = packh2((_Float16)l0, (_Float16)l1);
}

__device__ __forceinline__ void splitf16_8(const float4& a, const float4& b,
                                           uint4& uh, uint4& ul) {
    splitf16_2(a.x, a.y, uh.x, ul.x);
    splitf16_2(a.z, a.w, uh.y, ul.y);
    splitf16_2(b.x, b.y, uh.z, ul.z);
    splitf16_2(b.z, b.w, uh.w, ul.w);
}

// ---------- prep: 32 blocks, each a 64-k half-slab; LDS transpose -> fp16 fragment order ----------
__global__ __launch_bounds__(256) void k_prep(
    const float* __restrict__ Wq, const float* __restrict__ Wk,
    short* __restrict__ ws)
{
    __shared__ float wlds[64 * 36];    // [k 0..63][n 0..31], stride 36 floats
    const int b = blockIdx.x, tid = threadIdx.x;
    const float* __restrict__ src = (b < 16) ? Wq : Wk;
    const int k0 = (b & 15) * 64;
    const int nbase = (b < 16) ? 0 : 32;
#pragma unroll
    for (int it = 0; it < 2; ++it) {               // coalesced read 64x32 floats
        int f = it * 256 + tid;                    // float4 index
        int k = f >> 3, c4 = f & 7;
        float4 v = *(const float4*)(src + (size_t)(k0 + k) * DH + c4 * 4);
        *(float4*)&wlds[k * 36 + c4 * 4] = v;
    }
    __syncthreads();
    const int n = tid >> 3, kq = tid & 7;
    const int n_g = nbase + n;
    const int nt = n_g >> 4, ln = n_g & 15;
#pragma unroll
    for (int rep = 0; rep < 2; ++rep) {
        int kk = rep * 8 + kq;                     // k-quad within this 64-slab
        int k_g = k0 + kk * 4;
        float f0 = wlds[(kk * 4 + 0) * 36 + n];
        float f1 = wlds[(kk * 4 + 1) * 36 + n];
        float f2 = wlds[(kk * 4 + 2) * 36 + n];
        float f3 = wlds[(kk * 4 + 3) * 36 + n];
        uint2 ph;
        ph.x = packh2((_Float16)f0, (_Float16)f1); // RNE fp16, err <= 2^-12 rel
        ph.y = packh2((_Float16)f2, (_Float16)f3);
        int sub = k_g >> 5;                        // global 32-k subchunk 0..31
        int gq = (k_g >> 3) & 3, j0 = k_g & 7;
        int lane = gq * 16 + ln;
        size_t flat = ((size_t)(nt * 32 + sub)) * 512 + lane * 8 + j0;
        *(uint2*)(ws + flat) = ph;
    }
}

// ---------- fused main: TB=32, fp16 2-pass MFMA, dist-2 x prefetch + B-before-x issue order ----------
#define TB 32
#define XS2 136  // x LDS row stride in shorts (128 data + 8 pad) = 272 B
#define QS 68    // qk row stride in floats
#define ZS 40    // z row stride in shorts

__global__ __launch_bounds__(256, 3) void k_main(
    const float* __restrict__ x, const float* __restrict__ bq,
    const float* __restrict__ bk, const short* __restrict__ ws,
    const float* __restrict__ w, float* __restrict__ out)
{
    __shared__ __align__(16) short xh_s[2][TB * XS2];
    __shared__ __align__(16) short xl_s[2][TB * XS2];
    __shared__ __align__(16) float qk_f[TB * QS];
    __shared__ __align__(16) short zh_s[TB * ZS];
    __shared__ __align__(16) short zl_s[TB * ZS];
    __shared__ float lnA_f[TB];

    const int tid  = threadIdx.x;
    const int lane = tid & 63;
    const int wv   = __builtin_amdgcn_readfirstlane(tid >> 6);  // 0..3
    const int ln15 = lane & 15;
    const int g    = lane >> 4;                                  // 0..3
    const long t0  = (long)blockIdx.x * TB;

    const int nrow = wv * 16 + ln15;   // proj output column 0..63
    const float bias = (nrow < 32) ? bq[nrow] : bk[nrow - 32];

    // -------- Phase 1: C[32 tok][64] = x @ [Wq|Wk] (fp16 2-pass) --------
    // vmcnt discipline: B(p) issues BEFORE xpf(p+2), so the MFMA wait on B is
    // vmcnt(4) and never drains the in-flight x prefetch (in-order completion).
    const int kq = tid & 15;          // 8-k group 0..15 within 128-wide pair
    const int mr = tid >> 4;          // token row 0..15 (also handles mr+16)

    f32x4 acc0 = {0.f, 0.f, 0.f, 0.f};   // tokens 0..15
    f32x4 acc1 = {0.f, 0.f, 0.f, 0.f};   // tokens 16..31

    const short* wpB = ws + (size_t)(wv * 32) * 512 + lane * 8;
    const float* xr0 = x + (t0 + mr) * (size_t)E_DIM + kq * 8;
    const float* xr1 = x + (t0 + mr + 16) * (size_t)E_DIM + kq * 8;

    // two live x prefetch sets; pair k lives in set parity (k&1). B: bfr = current phase.
    float4 s0[4], s1[4];
    f16x8 bfr[4];
    {
        float4 t0v = *(const float4*)(xr0 + 0), t1v = *(const float4*)(xr0 + 4);
        float4 t2v = *(const float4*)(xr1 + 0), t3v = *(const float4*)(xr1 + 4);
        s1[0] = *(const float4*)(xr0 + 128);
        s1[1] = *(const float4*)(xr0 + 132);
        s1[2] = *(const float4*)(xr1 + 128);
        s1[3] = *(const float4*)(xr1 + 132);
#pragma unroll
        for (int j = 0; j < 4; ++j)
            bfr[j] = *(const f16x8*)(wpB + (size_t)j * 512);   // B(0)
        __builtin_amdgcn_sched_barrier(0);
        uint4 uh, ul;
        splitf16_8(t0v, t1v, uh, ul);
        *(uint4*)&xh_s[0][mr * XS2 + kq * 8] = uh;
        *(uint4*)&xl_s[0][mr * XS2 + kq * 8] = ul;
        splitf16_8(t2v, t3v, uh, ul);
        *(uint4*)&xh_s[0][(mr + 16) * XS2 + kq * 8] = uh;
        *(uint4*)&xl_s[0][(mr + 16) * XS2 + kq * 8] = ul;
    }

#pragma unroll
    for (int p = 0; p < 8; ++p) {
        __syncthreads();              // LDS buf (p&1) fully staged; prior reads of it done
        // issue x pair p+2 (AFTER bfr(p) in program order -> never drained early)
        if (p < 6) {
            float4* d = (p & 1) ? s1 : s0;
            d[0] = *(const float4*)(xr0 + (p + 2) * 128);
            d[1] = *(const float4*)(xr0 + (p + 2) * 128 + 4);
            d[2] = *(const float4*)(xr1 + (p + 2) * 128);
            d[3] = *(const float4*)(xr1 + (p + 2) * 128 + 4);
        }
        __builtin_amdgcn_sched_barrier(0);
        // MFMA cluster on LDS buf (p&1) with registered B(p); wait = vmcnt(4)
#pragma unroll
        for (int j = 0; j < 4; ++j) {
            f16x8 ah0 = *(const f16x8*)&xh_s[p & 1][ln15 * XS2 + j * 32 + g * 8];
            f16x8 al0 = *(const f16x8*)&xl_s[p & 1][ln15 * XS2 + j * 32 + g * 8];
            f16x8 ah1 = *(const f16x8*)&xh_s[p & 1][(ln15 + 16) * XS2 + j * 32 + g * 8];
            f16x8 al1 = *(const f16x8*)&xl_s[p & 1][(ln15 + 16) * XS2 + j * 32 + g * 8];
            acc0 = __builtin_amdgcn_mfma_f32_16x16x32_f16(ah0, bfr[j], acc0, 0, 0, 0);
            acc0 = __builtin_amdgcn_mfma_f32_16x16x32_f16(al0, bfr[j], acc0, 0, 0, 0);
            acc1 = __builtin_amdgcn_mfma_f32_16x16x32_f16(ah1, bfr[j], acc1, 0, 0, 0);
            acc1 = __builtin_amdgcn_mfma_f32_16x16x32_f16(al1, bfr[j], acc1, 0, 0, 0);
        }
        if (p < 7) {
            // prefetch B(p+1) at the tail: issued BEFORE next phase's x loads,
            // covered by split+ds_write+barrier (~L2 latency)
            f16x8 bnx[4];
#pragma unroll
            for (int j = 0; j < 4; ++j)
                bnx[j] = *(const f16x8*)(wpB + (size_t)((p + 1) * 4 + j) * 512);
            __builtin_amdgcn_sched_barrier(0);
            // stage pair p+1 (issued a full phase ago -> no vmcnt stall)
            const float4* s = ((p + 1) & 1) ? s1 : s0;
            uint4 uh, ul;
            splitf16_8(s[0], s[1], uh, ul);
            *(uint4*)&xh_s[(p + 1) & 1][mr * XS2 + kq * 8] = uh;
            *(uint4*)&xl_s[(p + 1) & 1][mr * XS2 + kq * 8] = ul;
            splitf16_8(s[2], s[3], uh, ul);
            *(uint4*)&xh_s[(p + 1) & 1][(mr + 16) * XS2 + kq * 8] = uh;
            *(uint4*)&xl_s[(p + 1) & 1][(mr + 16) * XS2 + kq * 8] = ul;
#pragma unroll
            for (int j = 0; j < 4; ++j) bfr[j] = bnx[j];
        }
    }

    // issue feature-w fp32 fragment loads; barrier phases below cover their latency
    float4 wfa[4], wfb[4];
#pragma unroll
    for (int i = 0; i < 4; ++i) {
        const int nf = (wv * 4 + i) * 16 + ln15;    // feature 0..255
        wfa[i] = *(const float4*)(w + (size_t)nf * DH + g * 8);
        wfb[i] = *(const float4*)(w + (size_t)nf * DH + g * 8 + 4);
    }

    // -------- Phase 2: +bias -> qk LDS (C/D layout: row(tok)=g*4+r, col=ln15) --------
#pragma unroll
    for (int r = 0; r < 4; ++r) {
        qk_f[(g * 4 + r) * QS + nrow]        = acc0[r] + bias;
        qk_f[(16 + g * 4 + r) * QS + nrow]   = acc1[r] + bias;
    }
    __syncthreads();

    // -------- Phase 3: z = q+k (fp16 split), lnA = -0.5(|q|^2+|k|^2); 32 tok x 8 grp --------
    {
        const int tok = tid >> 3, grp = tid & 7;
        float4 qv = *(const float4*)&qk_f[tok * QS + grp * 4];
        float4 kv = *(const float4*)&qk_f[tok * QS + 32 + grp * 4];
        float z0 = qv.x + kv.x, z1 = qv.y + kv.y, z2 = qv.z + kv.z, z3 = qv.w + kv.w;
        float pw = qv.x*qv.x + qv.y*qv.y + qv.z*qv.z + qv.w*qv.w
                 + kv.x*kv.x + kv.y*kv.y + kv.z*kv.z + kv.w*kv.w;
        uint2 ph, pl;
        splitf16_2(z0, z1, ph.x, pl.x);
        splitf16_2(z2, z3, ph.y, pl.y);
        *(uint2*)&zh_s[tok * ZS + grp * 4] = ph;
        *(uint2*)&zl_s[tok * ZS + grp * 4] = pl;
        pw += __shfl_xor(pw, 1);
        pw += __shfl_xor(pw, 2);
        pw += __shfl_xor(pw, 4);
        if (grp == 0) lnA_f[tok] = -0.5f * pw;
    }
    __syncthreads();

    // -------- Phase 4: S[32 tok][256] = z @ w^T (fp16 2-pass); wave wv: features wv*64.. --------
    f32x4 facc[4][2];
#pragma unroll
    for (int i = 0; i < 4; ++i)
#pragma unroll
        for (int mt = 0; mt < 2; ++mt) facc[i][mt] = (f32x4){0.f,0.f,0.f,0.f};

    f16x8 a_h[2], a_l[2];
#pragma unroll
    for (int mt = 0; mt < 2; ++mt) {
        a_h[mt] = *(const f16x8*)&zh_s[(mt * 16 + ln15) * ZS + g * 8];
        a_l[mt] = *(const f16x8*)&zl_s[(mt * 16 + ln15) * ZS + g * 8];
    }
#pragma unroll
    for (int i = 0; i < 4; ++i) {
        uint4 uw;
        uw.x = packh2((_Float16)wfa[i].x, (_Float16)wfa[i].y);
        uw.y = packh2((_Float16)wfa[i].z, (_Float16)wfa[i].w);
        uw.z = packh2((_Float16)wfb[i].x, (_Float16)wfb[i].y);
        uw.w = packh2((_Float16)wfb[i].z, (_Float16)wfb[i].w);
        f16x8 w8 = __builtin_bit_cast(f16x8, uw);
#pragma unroll
        for (int mt = 0; mt < 2; ++mt) {
            facc[i][mt] = __builtin_amdgcn_mfma_f32_16x16x32_f16(a_h[mt], w8, facc[i][mt], 0, 0, 0);
            facc[i][mt] = __builtin_amdgcn_mfma_f32_16x16x32_f16(a_l[mt], w8, facc[i][mt], 0, 0, 0);
        }
    }

    // -------- Phase 5: R = 0.5*(exp(lnA+s)+exp(lnA-s)) --------
    float lnAv[2][4];
#pragma unroll
    for (int mt = 0; mt < 2; ++mt)
#pragma unroll
        for (int r = 0; r < 4; ++r) lnAv[mt][r] = lnA_f[mt * 16 + g * 4 + r];

#pragma unroll
    for (int i = 0; i < 4; ++i) {
        const int n = (wv * 4 + i) * 16 + ln15;
#pragma unroll
        for (int mt = 0; mt < 2; ++mt) {
#pragma unroll
            for (int r = 0; r < 4; ++r) {
                float s = facc[i][mt][r];
                float R = 0.5f * (__expf(lnAv[mt][r] + s) + __expf(lnAv[mt][r] - s));
                __builtin_nontemporal_store(R, &out[(t0 + mt * 16 + g * 4 + r) * M_FEAT + n]);
            }
        }
    }
}

extern "C" void kernel_launch(void* const* d_in, const int* in_sizes, int n_in,
                              void* d_out, int out_size, void* d_ws, size_t ws_size,
                              hipStream_t stream) {
    const float* x  = (const float*)d_in[0];
    const float* Wq = (const float*)d_in[1];
    const float* bq = (const float*)d_in[2];
    const float* Wk = (const float*)d_in[3];
    const float* bk = (const float*)d_in[4];
    // d_in[5], d_in[6] = Wv, bv: dead in the reference
    const float* w  = (const float*)d_in[7];
    float* out = (float*)d_out;
    short* ws  = (short*)d_ws;   // 128 KB used (single fp16 weight panel)

    k_prep<<<dim3(32), dim3(256), 0, stream>>>(Wq, Wk, ws);
    k_main<<<dim3(BT / TB), dim3(256), 0, stream>>>(x, bq, bk, ws, w, out);
}